// Round 12
// baseline (372.372 us; speedup 1.0000x reference)
//
#include <hip/hip_runtime.h>

#define HSZ 64
#define ISZ 8
#define TSZ 512
#define BTILE 16   // batch rows per block; A = rows 0-7 (waves 0-7), B = rows 8-15 (waves 8-15)
#define NW 16      // waves per block (1024 threads) -> 4 waves/SIMD
#define KP 104     // k per row: [0,64) h | [64,72) x | zero pad; 208B row stride

typedef _Float16 f16;
typedef __attribute__((ext_vector_type(8))) _Float16 f16x8;
typedef __attribute__((ext_vector_type(4))) float f32x4;
typedef unsigned short u16;

__device__ __forceinline__ u16 f16bits(float f) {
    union { f16 h; u16 u; } v; v.h = (f16)f;
    return v.u;
}

// Role-split deterministic anti-phase LSTM.
// Operand-swapped MFMA: A-operand = weights (M = 16 gate rows), B = h/x (N = 16
// batch cols). Wave w: group grp = w>>3 (A: batch 0-7, B: batch 8-15), wg = w&7
// owns hidden [8wg, 8wg+8) via 2 gate-tiles. Phase 0: group A does ds_read+MFMA(t)
// while group B does act(t-1)+write (VALU). Phase 1: roles swap. Every barrier
// interval keeps DS+MFMA AND VALU pipes busy by construction. The other group's
// N-cols are concurrently-written garbage -- discarded, so output is
// deterministic (all consumed values barrier-ordered). Single H buffer.
// After MFMA, xor8 redistributes accs so each lane acts on exactly ONE unit:
//   grp A: p = lo8 ? a0 : shfl_xor(a1,8)   (unit batch lr&7,  hidden 8wg+lg+{0,4})
//   grp B: p = lo8 ? shfl_xor(a0,8) : a1   (unit batch lr|8,  hidden 8wg+lg+{0,4})
// Bias = MFMA C-in, pre-scaled by -log2e / -2log2e (act uses exp2 directly).
__global__ __launch_bounds__(1024, 4) void lstm_roles(
    const float* __restrict__ x,      // [B, T, I]
    const float* __restrict__ W_ih,   // [4H, I]
    const float* __restrict__ W_hh,   // [4H, H]
    const float* __restrict__ b_ih,   // [4H]
    const float* __restrict__ b_hh,   // [4H]
    const float* __restrict__ W_fc,   // [O, H]
    const float* __restrict__ b_fc,   // [O]
    float* __restrict__ out)          // [B, O]
{
    const int tid = threadIdx.x;
    const int w   = tid >> 6;         // wave 0..15
    const int wg  = w & 7;            // hidden-slice index within group
    const int grp = w >> 3;           // 0 = batch rows 0-7, 1 = rows 8-15
    const int l  = tid & 63;
    const int lr = l & 15;            // A: M-row sel / B,C: batch col
    const int lg = l >> 4;            // k-group
    const int B0 = blockIdx.x * BTILE;
    const bool lo8 = (lr < 8);

    __shared__ __align__(16) u16 H[BTILE][KP];   // [batch row][k] -- single buffer
    __shared__ float red[NW][8];

    for (int i = tid; i < BTILE * KP; i += 1024)
        ((u16*)H)[i] = 0;

    // ---- A-fragments (weights) for 2 tiles, pre-scaled; bias as C-in ----
    const int gate = lr & 3;
    const float sc = (gate == 2) ? -2.885390082f : -1.442695041f;
    f16x8 wa0[2], wa1[2], wa2[2];
    f32x4 bias4[2];
#pragma unroll
    for (int q = 0; q < 2; ++q) {
        const int n  = 2 * wg + q;                      // tile index 0..15
        const int gc = gate * HSZ + 4 * n + (lr >> 2);  // gate row in [0,256)
        {
            const float4 a = *reinterpret_cast<const float4*>(&W_hh[gc * HSZ + lg * 8]);
            const float4 b = *reinterpret_cast<const float4*>(&W_hh[gc * HSZ + lg * 8 + 4]);
            wa0[q][0] = (f16)(sc * a.x); wa0[q][1] = (f16)(sc * a.y);
            wa0[q][2] = (f16)(sc * a.z); wa0[q][3] = (f16)(sc * a.w);
            wa0[q][4] = (f16)(sc * b.x); wa0[q][5] = (f16)(sc * b.y);
            wa0[q][6] = (f16)(sc * b.z); wa0[q][7] = (f16)(sc * b.w);
        }
        {
            const float4 a = *reinterpret_cast<const float4*>(&W_hh[gc * HSZ + 32 + lg * 8]);
            const float4 b = *reinterpret_cast<const float4*>(&W_hh[gc * HSZ + 32 + lg * 8 + 4]);
            wa1[q][0] = (f16)(sc * a.x); wa1[q][1] = (f16)(sc * a.y);
            wa1[q][2] = (f16)(sc * a.z); wa1[q][3] = (f16)(sc * a.w);
            wa1[q][4] = (f16)(sc * b.x); wa1[q][5] = (f16)(sc * b.y);
            wa1[q][6] = (f16)(sc * b.z); wa1[q][7] = (f16)(sc * b.w);
        }
#pragma unroll
        for (int j = 0; j < 8; ++j) wa2[q][j] = (f16)0.0f;
        if (lg == 0) {                // k 64..71 -> x weights; zero for lg>=1
            const float4 a = *reinterpret_cast<const float4*>(&W_ih[gc * ISZ]);
            const float4 b = *reinterpret_cast<const float4*>(&W_ih[gc * ISZ + 4]);
            wa2[q][0] = (f16)(sc * a.x); wa2[q][1] = (f16)(sc * a.y);
            wa2[q][2] = (f16)(sc * a.z); wa2[q][3] = (f16)(sc * a.w);
            wa2[q][4] = (f16)(sc * b.x); wa2[q][5] = (f16)(sc * b.y);
            wa2[q][6] = (f16)(sc * b.z); wa2[q][7] = (f16)(sc * b.w);
        }
        const int hc = 4 * n + lg;    // tile q's hidden unit for this lane
#pragma unroll
        for (int r = 0; r < 4; ++r) {
            const float s = (r == 2) ? -2.885390082f : -1.442695041f;
            bias4[q][r] = s * (b_ih[r * HSZ + hc] + b_hh[r * HSZ + hc]);
        }
    }

    __syncthreads();  // zeroing visible

    // x staging: wave 0 stages rows 0-7, wave 8 stages rows 8-15 (all 64 lanes)
    const float* xptr = x + (size_t)(B0 + grp * 8 + (l >> 3)) * TSZ * ISZ + (l & 7);
    u16* xsp = &H[grp * 8 + (l >> 3)][HSZ + (l & 7)];
    if (wg == 0)
        *xsp = f16bits(xptr[0]);     // x(0)
    __syncthreads();

    // this lane's owned unit after xor8 redistribution
    const int brow = grp ? (lr | 8) : (lr & 7);
    const int hcol = 8 * wg + lg + (lo8 ? 0 : 4);
    const u16* rdb = &H[lr][lg * 8];
    u16* wrp = &H[brow][hcol];

    float c = 0.0f, h = 0.0f;
    f32x4 a0, a1;                     // preacts, carried MFMA-phase -> act-phase
    const float L2 = 2.885390082f;

#define MFMA_BLOCK()                                                            \
    {                                                                           \
        const f16x8 b0 = *reinterpret_cast<const f16x8*>(rdb);                  \
        const f16x8 b1 = *reinterpret_cast<const f16x8*>(rdb + 32);             \
        f16x8 b2 = {};                                                          \
        if (lg == 0)                                                            \
            b2 = *reinterpret_cast<const f16x8*>(rdb + 64);                     \
        __builtin_amdgcn_s_setprio(1);                                          \
        a0 = __builtin_amdgcn_mfma_f32_16x16x32_f16(wa2[0], b2, bias4[0], 0, 0, 0); \
        a1 = __builtin_amdgcn_mfma_f32_16x16x32_f16(wa2[1], b2, bias4[1], 0, 0, 0); \
        a0 = __builtin_amdgcn_mfma_f32_16x16x32_f16(wa0[0], b0, a0, 0, 0, 0);   \
        a1 = __builtin_amdgcn_mfma_f32_16x16x32_f16(wa0[1], b0, a1, 0, 0, 0);   \
        a0 = __builtin_amdgcn_mfma_f32_16x16x32_f16(wa1[0], b1, a0, 0, 0, 0);   \
        a1 = __builtin_amdgcn_mfma_f32_16x16x32_f16(wa1[1], b1, a1, 0, 0, 0);   \
        __builtin_amdgcn_s_setprio(0);                                          \
    }

#define ACT_BLOCK()                                                             \
    {                                                                           \
        float p0, p1, p2, p3;                                                   \
        if (grp == 0) {                                                         \
            const float s0 = __shfl_xor(a1[0], 8);                              \
            const float s1 = __shfl_xor(a1[1], 8);                              \
            const float s2 = __shfl_xor(a1[2], 8);                              \
            const float s3 = __shfl_xor(a1[3], 8);                              \
            p0 = lo8 ? a0[0] : s0;  p1 = lo8 ? a0[1] : s1;                      \
            p2 = lo8 ? a0[2] : s2;  p3 = lo8 ? a0[3] : s3;                      \
        } else {                                                                \
            const float s0 = __shfl_xor(a0[0], 8);                              \
            const float s1 = __shfl_xor(a0[1], 8);                              \
            const float s2 = __shfl_xor(a0[2], 8);                              \
            const float s3 = __shfl_xor(a0[3], 8);                              \
            p0 = lo8 ? s0 : a1[0];  p1 = lo8 ? s1 : a1[1];                      \
            p2 = lo8 ? s2 : a1[2];  p3 = lo8 ? s3 : a1[3];                      \
        }                                                                       \
        const float ea = __builtin_amdgcn_exp2f(p0);                            \
        const float eb = __builtin_amdgcn_exp2f(p1);                            \
        const float ed = __builtin_amdgcn_exp2f(p2);                            \
        const float es = __builtin_amdgcn_exp2f(p3);                            \
        const float A1 = 1.0f + ea, B1 = 1.0f + eb, D1 = 1.0f + ed;             \
        const float R1 = __builtin_amdgcn_rcpf(A1 * B1 * D1);                   \
        c = fmaf(c * A1, D1, (1.0f - ed) * B1) * R1;                            \
        const float eu = __builtin_amdgcn_exp2f(-L2 * c);                       \
        const float R2 = __builtin_amdgcn_rcpf((1.0f + es) * (1.0f + eu));      \
        h = (1.0f - eu) * R2;                                                   \
        *wrp = f16bits(h);                                                      \
    }

    for (int t = 0; t < TSZ; ++t) {
        // ===== phase 0: A: MFMA(t) ===== B: act(t-1) + stage x_B(t) =====
        if (grp == 0) {
            MFMA_BLOCK()
        } else {
            float xv = 0.0f;
            if (wg == 0 && t > 0)
                xv = xptr[(size_t)t * ISZ];      // load early, hidden under act
            if (t > 0)
                ACT_BLOCK()
            if (wg == 0 && t > 0)
                *xsp = f16bits(xv);
        }
        __syncthreads();
        // ===== phase 1: B: MFMA(t) ===== A: act(t) + stage x_A(t+1) =====
        if (grp == 1) {
            MFMA_BLOCK()
        } else {
            float xv = 0.0f;
            if (wg == 0 && t + 1 < TSZ)
                xv = xptr[(size_t)(t + 1) * ISZ];
            ACT_BLOCK()
            if (wg == 0 && t + 1 < TSZ)
                *xsp = f16bits(xv);
        }
        __syncthreads();
    }
    // epilogue: B's act(511)
    if (grp == 1)
        ACT_BLOCK()
#undef MFMA_BLOCK
#undef ACT_BLOCK

    // ---- final FC: out[b] = sum_h h(b,hu) * W_fc[hu] + b_fc ----
    // lane's unit: (batch brow, hidden hcol). xor8 pairs the 2 tiles (same batch);
    // xor16/32 sum over lg -> lane l<8 holds the wave's 8-hidden partial of batch
    // (l&7) within its group.
    float v = h * W_fc[hcol];
    v += __shfl_xor(v, 8);
    v += __shfl_xor(v, 16);
    v += __shfl_xor(v, 32);
    if (l < 8) red[w][l] = v;
    __syncthreads();
    if (tid < BTILE) {
        float s = b_fc[0];
        const int base = (tid >> 3) * 8;   // group A waves 0-7, group B waves 8-15
#pragma unroll
        for (int ww = 0; ww < 8; ++ww) s += red[base + ww][tid & 7];
        out[B0 + tid] = s;
    }
}

extern "C" void kernel_launch(void* const* d_in, const int* in_sizes, int n_in,
                              void* d_out, int out_size, void* d_ws, size_t ws_size,
                              hipStream_t stream) {
    const float* x    = (const float*)d_in[0];
    const float* W_ih = (const float*)d_in[1];
    const float* W_hh = (const float*)d_in[2];
    const float* b_ih = (const float*)d_in[3];
    const float* b_hh = (const float*)d_in[4];
    const float* W_fc = (const float*)d_in[5];
    const float* b_fc = (const float*)d_in[6];
    float* out = (float*)d_out;

    const int B = in_sizes[0] / (TSZ * ISZ);  // 4096
    lstm_roles<<<B / BTILE, NW * 64, 0, stream>>>(x, W_ih, W_hh, b_ih, b_hh, W_fc, b_fc, out);
}

// Round 13
// 286.807 us; speedup vs baseline: 1.2983x; 1.2983x over previous
//
#include <hip/hip_runtime.h>

#define HSZ 64
#define ISZ 8
#define TSZ 512
#define BTILE 16   // batch rows per block (all 16 N-cols valid)
#define NW 8       // waves per block (512 threads); wave w owns hidden [8w, 8w+8)
#define KP 72      // u16 per row: [0,64) h + 8 pad; 144 B row stride

typedef _Float16 f16;
typedef __attribute__((ext_vector_type(8))) _Float16 f16x8;
typedef __attribute__((ext_vector_type(4))) float f32x4;
typedef unsigned short u16;
typedef unsigned int u32;

__device__ __forceinline__ u16 f16bits(float f) {
    union { f16 h; u16 u; } v; v.h = (f16)f;
    return v.u;
}

// 2-tiles-per-wave operand-swapped MFMA LSTM, x via global->register.
// A = weights (M = 16 gate rows), B = h (LDS) / x (register), N = 16 batch.
// Tile q of wave w: gc(m) = (m&3)*64 + 8w + 2*(m>>2) + q -> lane (lr,lg) owns
// units (batch lr, hidden 8w+2lg) [q=0] and (batch lr, hidden 8w+2lg+1) [q=1]:
// ADJACENT cols -> the two h-values pack into one conflict-free ds_write_b32.
// b0/b1 (h K-tiles) are shared by both gate-tiles: 2 ds_read_b128 per wave per
// step (vs r9's 3 unshared). x never touches LDS: all lanes load x[B0+lr][t][0..8)
// from global (dup lanes hit L1), convert to f16x8; wa2 is zero for k>=8 so the
// garbage B-slices contribute exactly 0. Bias = MFMA C-in, pre-scaled by
// -log2e / -2log2e. Double-buffered H, ONE barrier per step.
__global__ __launch_bounds__(512) void lstm_gx(
    const float* __restrict__ x,      // [B, T, I]
    const float* __restrict__ W_ih,   // [4H, I]
    const float* __restrict__ W_hh,   // [4H, H]
    const float* __restrict__ b_ih,   // [4H]
    const float* __restrict__ b_hh,   // [4H]
    const float* __restrict__ W_fc,   // [O, H]
    const float* __restrict__ b_fc,   // [O]
    float* __restrict__ out)          // [B, O]
{
    const int tid = threadIdx.x;
    const int w  = tid >> 6;          // wave 0..7
    const int l  = tid & 63;
    const int lr = l & 15;            // A: M-row sel / B,C: batch col
    const int lg = l >> 4;            // k-group
    const int B0 = blockIdx.x * BTILE;

    __shared__ __align__(16) u16 H[2][BTILE][KP];  // [buf][batch row][k]
    __shared__ float red[NW][BTILE];

    for (int i = tid; i < 2 * BTILE * KP / 2; i += 512)
        ((u32*)H)[i] = 0;

    // ---- A-fragments (weights) for 2 tiles, pre-scaled; bias as C-in ----
    const int gate = lr & 3;
    const int slot = lr >> 2;
    const float sc = (gate == 2) ? -2.885390082f : -1.442695041f;
    f16x8 wa0[2], wa1[2], wa2[2];
    f32x4 bias4[2];
#pragma unroll
    for (int q = 0; q < 2; ++q) {
        const int gc = gate * HSZ + 8 * w + 2 * slot + q;   // gate row in [0,256)
        {
            const float4 a = *reinterpret_cast<const float4*>(&W_hh[gc * HSZ + lg * 8]);
            const float4 b = *reinterpret_cast<const float4*>(&W_hh[gc * HSZ + lg * 8 + 4]);
            wa0[q][0] = (f16)(sc * a.x); wa0[q][1] = (f16)(sc * a.y);
            wa0[q][2] = (f16)(sc * a.z); wa0[q][3] = (f16)(sc * a.w);
            wa0[q][4] = (f16)(sc * b.x); wa0[q][5] = (f16)(sc * b.y);
            wa0[q][6] = (f16)(sc * b.z); wa0[q][7] = (f16)(sc * b.w);
        }
        {
            const float4 a = *reinterpret_cast<const float4*>(&W_hh[gc * HSZ + 32 + lg * 8]);
            const float4 b = *reinterpret_cast<const float4*>(&W_hh[gc * HSZ + 32 + lg * 8 + 4]);
            wa1[q][0] = (f16)(sc * a.x); wa1[q][1] = (f16)(sc * a.y);
            wa1[q][2] = (f16)(sc * a.z); wa1[q][3] = (f16)(sc * a.w);
            wa1[q][4] = (f16)(sc * b.x); wa1[q][5] = (f16)(sc * b.y);
            wa1[q][6] = (f16)(sc * b.z); wa1[q][7] = (f16)(sc * b.w);
        }
#pragma unroll
        for (int j = 0; j < 8; ++j) wa2[q][j] = (f16)0.0f;
        if (lg == 0) {                // A k-slice [0,8) = x weights; k>=8 zero
            const float4 a = *reinterpret_cast<const float4*>(&W_ih[gc * ISZ]);
            const float4 b = *reinterpret_cast<const float4*>(&W_ih[gc * ISZ + 4]);
            wa2[q][0] = (f16)(sc * a.x); wa2[q][1] = (f16)(sc * a.y);
            wa2[q][2] = (f16)(sc * a.z); wa2[q][3] = (f16)(sc * a.w);
            wa2[q][4] = (f16)(sc * b.x); wa2[q][5] = (f16)(sc * b.y);
            wa2[q][6] = (f16)(sc * b.z); wa2[q][7] = (f16)(sc * b.w);
        }
        const int hq = 8 * w + 2 * lg + q;   // this lane's unit-q hidden index
#pragma unroll
        for (int r = 0; r < 4; ++r) {
            const float s = (r == 2) ? -2.885390082f : -1.442695041f;
            bias4[q][r] = s * (b_ih[r * HSZ + hq] + b_hh[r * HSZ + hq]);
        }
    }

    __syncthreads();  // zeroing visible (h(0)=0)

    // hoisted LDS offsets
    const u16* rd0 = &H[0][lr][lg * 8];
    const u16* rd1 = &H[1][lr][lg * 8];
    u32* wr0 = (u32*)&H[0][lr][8 * w + 2 * lg];
    u32* wr1 = (u32*)&H[1][lr][8 * w + 2 * lg];

    // x: every lane loads batch row lr (lanes with same lr dup -> L1 broadcast)
    const float* xrow = x + (size_t)(B0 + lr) * TSZ * ISZ;
    float4 xa = *reinterpret_cast<const float4*>(xrow);
    float4 xb = *reinterpret_cast<const float4*>(xrow + 4);

    float c0 = 0.f, h0 = 0.f, c1 = 0.f, h1 = 0.f;
    const float L2 = 2.885390082f;

#define ACT(ACC, CC, HH)                                                       \
    {                                                                          \
        const float ea = __builtin_amdgcn_exp2f((ACC)[0]);                     \
        const float eb = __builtin_amdgcn_exp2f((ACC)[1]);                     \
        const float ed = __builtin_amdgcn_exp2f((ACC)[2]);                     \
        const float es = __builtin_amdgcn_exp2f((ACC)[3]);                     \
        const float A1 = 1.0f + ea, B1 = 1.0f + eb, D1 = 1.0f + ed;            \
        const float R1 = __builtin_amdgcn_rcpf(A1 * B1 * D1);                  \
        CC = fmaf(CC * A1, D1, (1.0f - ed) * B1) * R1;                         \
        const float eu = __builtin_amdgcn_exp2f(-L2 * CC);                     \
        const float R2 = __builtin_amdgcn_rcpf((1.0f + es) * (1.0f + eu));     \
        HH = (1.0f - eu) * R2;                                                 \
    }

#define STEP(RD, WR, T, GUARD)                                                 \
    {                                                                          \
        f16x8 b2;                                                              \
        b2[0] = (f16)xa.x; b2[1] = (f16)xa.y; b2[2] = (f16)xa.z;               \
        b2[3] = (f16)xa.w; b2[4] = (f16)xb.x; b2[5] = (f16)xb.y;               \
        b2[6] = (f16)xb.z; b2[7] = (f16)xb.w;                                  \
        if (GUARD) {  /* prefetch x(T+1), hidden under MFMA+act */             \
            xa = *reinterpret_cast<const float4*>(xrow + (size_t)(T + 1) * ISZ);     \
            xb = *reinterpret_cast<const float4*>(xrow + (size_t)(T + 1) * ISZ + 4); \
        }                                                                      \
        const f16x8 b0 = *reinterpret_cast<const f16x8*>(RD);                  \
        const f16x8 b1 = *reinterpret_cast<const f16x8*>(RD + 32);             \
        f32x4 a0 = __builtin_amdgcn_mfma_f32_16x16x32_f16(wa2[0], b2, bias4[0], 0, 0, 0); \
        f32x4 a1 = __builtin_amdgcn_mfma_f32_16x16x32_f16(wa2[1], b2, bias4[1], 0, 0, 0); \
        a0 = __builtin_amdgcn_mfma_f32_16x16x32_f16(wa0[0], b0, a0, 0, 0, 0);  \
        a1 = __builtin_amdgcn_mfma_f32_16x16x32_f16(wa0[1], b0, a1, 0, 0, 0);  \
        a0 = __builtin_amdgcn_mfma_f32_16x16x32_f16(wa1[0], b1, a0, 0, 0, 0);  \
        a1 = __builtin_amdgcn_mfma_f32_16x16x32_f16(wa1[1], b1, a1, 0, 0, 0);  \
        ACT(a0, c0, h0)                                                        \
        ACT(a1, c1, h1)                                                        \
        *(WR) = (u32)f16bits(h0) | ((u32)f16bits(h1) << 16);                   \
        __syncthreads();                                                       \
    }

    for (int t = 0; t < TSZ; t += 2) {
        // step t: read buf0, write h into buf1. x(t+1) always exists (t+1<=511).
        STEP(rd0, wr1, t, true)
        // step t+1: read buf1, write into buf0. x(t+2) exists unless t == 510.
        STEP(rd1, wr0, t + 1, t < TSZ - 2)
    }
#undef STEP
#undef ACT

    // ---- final FC: out[b] = sum_h h(b,hu)*W_fc[hu] + b_fc ----
    const int hc = 8 * w + 2 * lg;
    float v = fmaf(h0, W_fc[hc], h1 * W_fc[hc + 1]);
    v += __shfl_xor(v, 16);     // sum over lg (same lr)
    v += __shfl_xor(v, 32);
    if (l < 16) red[w][lr] = v; // wave's 8-hidden partial for batch lr
    __syncthreads();
    if (tid < BTILE) {
        float s = b_fc[0];
#pragma unroll
        for (int ww = 0; ww < NW; ++ww) s += red[ww][tid];
        out[B0 + tid] = s;
    }
}

extern "C" void kernel_launch(void* const* d_in, const int* in_sizes, int n_in,
                              void* d_out, int out_size, void* d_ws, size_t ws_size,
                              hipStream_t stream) {
    const float* x    = (const float*)d_in[0];
    const float* W_ih = (const float*)d_in[1];
    const float* W_hh = (const float*)d_in[2];
    const float* b_ih = (const float*)d_in[3];
    const float* b_hh = (const float*)d_in[4];
    const float* W_fc = (const float*)d_in[5];
    const float* b_fc = (const float*)d_in[6];
    float* out = (float*)d_out;

    const int B = in_sizes[0] / (TSZ * ISZ);  // 4096
    lstm_gx<<<B / BTILE, NW * 64, 0, stream>>>(x, W_ih, W_hh, b_ih, b_hh, W_fc, b_fc, out);
}